// Round 6
// baseline (196.372 us; speedup 1.0000x reference)
//
#include <hip/hip_runtime.h>
#include <hip/hip_fp16.h>

// Affinity propagation: 24 Jacobi iterations of an 8-neighbor weighted stencil.
// OFFSETS (dy,dx): (-1,-1),(-1,0),(-1,1),(0,-1),(0,1),(1,-1),(1,0),(1,1)
// R6: FUSE=4 per launch; 400 blocks x 3 tiles each, with a 2-deep register
// prefetch pipeline: tile t+1's weights/bias/state loads are issued before
// tile t's compute iterations, so global memory streams during LDS compute
// (fixes the grid-wide stage-phase / compute-phase serialization seen in R5).

#define EPSV 1e-6f

#define TILE_H 32
#define TILE_W 64
#define FUSE   4
#define IN_H   (TILE_H + 2 * FUSE)      // 40
#define IN_W   (TILE_W + 2 * FUSE)      // 72
#define BUF_H  (IN_H + 2)               // 42 (zero ring)
#define BUF_W  76                       // 74 padded -> rows 16B-aligned
#define QPR    (IN_W / 4)               // 18 quads per row
#define NQUAD  (IN_H * QPR)             // 720
#define NSLOT  3                        // ceil(720/256)
#define NTILE  3
#define NBLK   400                      // 1200 tiles / NTILE

typedef __attribute__((ext_vector_type(8))) _Float16 half8;
typedef __attribute__((ext_vector_type(4))) _Float16 half4;

// ---------------------------------------------------------------------------
// Kernel 1: normalize guidance -> fp16 weights (AoS), fp16 bias, fp16 state.
// ---------------------------------------------------------------------------
__global__ __launch_bounds__(256) void precompute_kernel(
    const float* __restrict__ guidance, const float* __restrict__ raw,
    half8* __restrict__ wgt, _Float16* __restrict__ bias,
    _Float16* __restrict__ state, int B, int H, int W)
{
    int idx = blockIdx.x * blockDim.x + threadIdx.x;
    int total = B * H * W;
    if (idx >= total) return;
    int x = idx % W;
    int y = (idx / W) % H;
    int b = idx / (W * H);

    const int dy[8] = {-1,-1,-1, 0, 0, 1, 1, 1};
    const int dx[8] = {-1, 0, 1,-1, 1,-1, 0, 1};

    float g[8];
    float s = 0.f;
#pragma unroll
    for (int c = 0; c < 8; ++c) {
        int yy = y + dy[c], xx = x + dx[c];
        float v = 0.f;
        if (yy >= 0 && yy < H && xx >= 0 && xx < W)
            v = guidance[(((size_t)b * 8 + c) * H + yy) * W + xx];
        g[c] = v;
        s += fabsf(v);
    }
    float inv = 1.f / fmaxf(s, EPSV);
    float wsum = 0.f;
#pragma unroll
    for (int c = 0; c < 8; ++c) { g[c] *= inv; wsum += g[c]; }

    half8 hw;
#pragma unroll
    for (int c = 0; c < 8; ++c) hw[c] = (_Float16)g[c];
    wgt[idx] = hw;

    float r = raw[idx];
    bias[idx]  = (_Float16)((1.f - wsum) * r);
    state[idx] = (_Float16)r;
}

// ---------------------------------------------------------------------------
// Prefetch one tile's per-slot weights/bias/state into registers.
// ---------------------------------------------------------------------------
__device__ __forceinline__ void prefetch_tile(
    int tile, const _Float16* __restrict__ src,
    const half8* __restrict__ wgt, const _Float16* __restrict__ bias,
    const int (&ry)[NSLOT], const int (&rx0)[NSLOT], const bool (&act)[NSLOT],
    half8 (&pw)[NSLOT][4], half4 (&pb)[NSLOT], half4 (&ps)[NSLOT])
{
    const int H = 480, W = 640, tilesX = 10, tilesY = 15;
    int tx = tile % tilesX;
    int tmp = tile / tilesX;
    int ty = tmp % tilesY;
    int b  = tmp / tilesY;
    int x0 = tx * TILE_W - FUSE;
    int y0 = ty * TILE_H - FUSE;
    size_t plane = (size_t)b * H * W;

#pragma unroll
    for (int j = 0; j < NSLOT; ++j) {
        int gy = y0 + ry[j], gx = x0 + rx0[j];
        bool ok = act[j] && gy >= 0 && gy < H && gx >= 0 && gx < W;
        half8 z;
#pragma unroll
        for (int c = 0; c < 8; ++c) z[c] = (_Float16)0.f;
        half4 z4;
#pragma unroll
        for (int c = 0; c < 4; ++c) z4[c] = (_Float16)0.f;
        pw[j][0] = z; pw[j][1] = z; pw[j][2] = z; pw[j][3] = z;
        pb[j] = z4; ps[j] = z4;
        if (ok) {
            size_t gb = plane + (size_t)gy * W + gx;
            const half8* wp = wgt + gb;                 // 64B contiguous
            pw[j][0] = wp[0]; pw[j][1] = wp[1];
            pw[j][2] = wp[2]; pw[j][3] = wp[3];
            pb[j] = *(const half4*)(bias + gb);
            ps[j] = *(const half4*)(src + gb);
        }
    }
}

// ---------------------------------------------------------------------------
// Kernel 2: each block runs NTILE tiles; per tile, FUSE fused Jacobi
// iterations in LDS (zero ring, full-interior recompute: after k iters,
// pixels >= k from the buffer edge are exact -> center TILE exact at k=FUSE).
// Tile t+1's global loads are issued before tile t's compute -> memory
// streams under LDS/VALU work. Out-of-image px have w=0,b=0 -> stay 0.
// ---------------------------------------------------------------------------
template<bool LAST>
__global__ __launch_bounds__(256, 2) void prop_fused_kernel(
    const _Float16* __restrict__ src, const half8* __restrict__ wgt,
    const _Float16* __restrict__ bias, _Float16* __restrict__ dst,
    float* __restrict__ dst32)
{
    const int H = 480, W = 640, tilesX = 10, tilesY = 15;
    __shared__ __align__(16) float bufA[BUF_H][BUF_W];
    __shared__ __align__(16) float bufB[BUF_H][BUF_W];
    int tid = threadIdx.x;

    // Slot geometry (tile-independent).
    int  ry[NSLOT], rx0[NSLOT], loff[NSLOT];
    bool act[NSLOT], core[NSLOT];
#pragma unroll
    for (int j = 0; j < NSLOT; ++j) {
        int q = j * 256 + tid;
        act[j] = q < NQUAD;
        int qq = act[j] ? q : 0;
        ry[j]  = qq / QPR;
        rx0[j] = (qq % QPR) * 4;
        loff[j] = ry[j] * BUF_W + rx0[j];
        core[j] = act[j] && ry[j] >= FUSE && ry[j] < FUSE + TILE_H &&
                  rx0[j] >= FUSE && rx0[j] < FUSE + TILE_W;
    }

    for (int i = tid; i < BUF_H * BUF_W; i += 256) {
        (&bufA[0][0])[i] = 0.f;
        (&bufB[0][0])[i] = 0.f;
    }

    // Double-buffered prefetch register sets; indices become compile-time
    // constants after full unroll of the tile loop (rule #20).
    half8 pw[2][NSLOT][4];
    half4 pb[2][NSLOT];
    half4 ps[2][NSLOT];
    prefetch_tile(blockIdx.x, src, wgt, bias, ry, rx0, act,
                  pw[0], pb[0], ps[0]);
    __syncthreads();   // zero-fill complete before staging

#pragma unroll
    for (int t = 0; t < NTILE; ++t) {
        const int cs = t & 1;
        const int ns = cs ^ 1;
        const int tile = blockIdx.x + t * NBLK;

        // Stage current tile's state into bufA interior.
#pragma unroll
        for (int j = 0; j < NSLOT; ++j) {
            if (act[j]) {
                float* d = &bufA[0][0] + loff[j] + BUF_W + 1;
                d[0] = (float)ps[cs][j][0]; d[1] = (float)ps[cs][j][1];
                d[2] = (float)ps[cs][j][2]; d[3] = (float)ps[cs][j][3];
            }
        }
        __syncthreads();

        // Issue next tile's global loads; first use is next staging, so the
        // compiler's vmcnt wait lands after this tile's compute.
        if (t + 1 < NTILE)
            prefetch_tile(tile + NBLK, src, wgt, bias, ry, rx0, act,
                          pw[ns], pb[ns], ps[ns]);

        // Output addressing for this tile.
        int tx = tile % tilesX;
        int tmp = tile / tilesX;
        int ty = tmp % tilesY;
        int b  = tmp / tilesY;
        int x0 = tx * TILE_W - FUSE;
        int y0 = ty * TILE_H - FUSE;
        size_t plane = (size_t)b * H * W;

#pragma unroll
        for (int k = 0; k < FUSE; ++k) {
            const float* cur = (k & 1) ? &bufB[0][0] : &bufA[0][0];
            float* nxt       = (k & 1) ? &bufA[0][0] : &bufB[0][0];
#pragma unroll
            for (int j = 0; j < NSLOT; ++j) {
                const float* up = cur + loff[j];
                const float* ct = up + BUF_W;
                const float* dn = ct + BUF_W;
                float4 u4 = *(const float4*)up;  float2 u2 = *(const float2*)(up + 4);
                float4 c4 = *(const float4*)ct;  float2 c2 = *(const float2*)(ct + 4);
                float4 d4 = *(const float4*)dn;  float2 d2 = *(const float2*)(dn + 4);
                float u[6]  = {u4.x, u4.y, u4.z, u4.w, u2.x, u2.y};
                float cc[6] = {c4.x, c4.y, c4.z, c4.w, c2.x, c2.y};
                float dd[6] = {d4.x, d4.y, d4.z, d4.w, d2.x, d2.y};
                float acc[4];
#pragma unroll
                for (int i = 0; i < 4; ++i) {
                    half8 hw = pw[cs][j][i];
                    float a = (float)pb[cs][j][i];
                    a += (float)hw[0] * u[i]  + (float)hw[1] * u[i + 1] + (float)hw[2] * u[i + 2];
                    a += (float)hw[3] * cc[i] + (float)hw[4] * cc[i + 2];
                    a += (float)hw[5] * dd[i] + (float)hw[6] * dd[i + 1] + (float)hw[7] * dd[i + 2];
                    acc[i] = a;
                }
                if (k < FUSE - 1) {
                    if (act[j]) {
                        float* o = nxt + loff[j] + BUF_W + 1;
                        o[0] = acc[0]; o[1] = acc[1]; o[2] = acc[2]; o[3] = acc[3];
                    }
                } else {
                    if (core[j]) {
                        size_t gb = plane + (size_t)(y0 + ry[j]) * W + (x0 + rx0[j]);
                        if (LAST) {
                            *(float4*)(dst32 + gb) =
                                make_float4(acc[0], acc[1], acc[2], acc[3]);
                        } else {
                            half4 hv;
                            hv[0] = (_Float16)acc[0]; hv[1] = (_Float16)acc[1];
                            hv[2] = (_Float16)acc[2]; hv[3] = (_Float16)acc[3];
                            *(half4*)(dst + gb) = hv;
                        }
                    }
                }
            }
            if (k < FUSE - 1) __syncthreads();
        }
        // No barrier needed here: next staging writes bufA (last read at k=2,
        // fenced by the k=2 barrier); k=3 reads bufB only, and the
        // post-staging barrier orders all k=3 reads before k=0 writes bufB.
    }
}

// ---------------------------------------------------------------------------
extern "C" void kernel_launch(void* const* d_in, const int* in_sizes, int n_in,
                              void* d_out, int out_size, void* d_ws, size_t ws_size,
                              hipStream_t stream) {
    const float* guidance = (const float*)d_in[0];
    const float* raw      = (const float*)d_in[1];
    float* out = (float*)d_out;

    const int B = 8, H = 480, W = 640;
    const size_t npix = (size_t)B * H * W;

    // Workspace: wgt half8 (npix*16B) | bias fp16 | p0 fp16 | p1 fp16
    half8*    wgt  = (half8*)d_ws;
    _Float16* bias = (_Float16*)((char*)d_ws + npix * sizeof(half8));
    _Float16* p0   = bias + npix;
    _Float16* p1   = p0 + npix;

    {
        int blocks = (int)((npix + 255) / 256);
        precompute_kernel<<<blocks, 256, 0, stream>>>(guidance, raw, wgt, bias,
                                                      p0, B, H, W);
    }

    // 6 launches x FUSE=4 = 24 iterations; fp16 state ping-pong, last writes f32.
    _Float16* a = p0;
    _Float16* bb = p1;
    for (int t = 0; t < 5; ++t) {
        prop_fused_kernel<false><<<NBLK, 256, 0, stream>>>(a, wgt, bias, bb,
                                                           nullptr);
        _Float16* sw = a; a = bb; bb = sw;
    }
    prop_fused_kernel<true><<<NBLK, 256, 0, stream>>>(a, wgt, bias, nullptr,
                                                      out);
}

// Round 7
// 104.494 us; speedup vs baseline: 1.8793x; 1.8793x over previous
//
#include <hip/hip_runtime.h>
#include <hip/hip_fp16.h>

// Affinity propagation: 24 Jacobi iterations of an 8-neighbor weighted stencil.
// OFFSETS (dy,dx): (-1,-1),(-1,0),(-1,1),(0,-1),(0,1),(1,-1),(1,0),(1,1)
// R7: register-resident state. Thread owns 4x4 px; block = 16x16 threads =
// 64x64 tile; FUSE=8 iterations per launch (3 launches). Horizontal neighbor
// exchange via DPP row_shr/row_shl (VALU, bound_ctrl -> 0 at tile edge);
// vertical via 2 LDS writes + 2 reads (b128) per thread-iter, ping-ponged.
// Weights (fp16 AoS) + bias live in registers for the whole launch.

#define EPSV 1e-6f
#define FUSE   8
#define CORE   48                 // output core per 64x64 tile
#define TXN    14                 // ceil(640/48)
#define TYN    10                 // 480/48
#define NBLK   (8 * TXN * TYN)    // 1120

typedef __attribute__((ext_vector_type(8))) _Float16 half8;
typedef __attribute__((ext_vector_type(4))) _Float16 half4;

__device__ __forceinline__ float dpp_from_left(float v) {
    // lane i gets lane i-1's v (within 16-lane DPP row); qx==0 -> 0.
    int r = __builtin_amdgcn_update_dpp(0, __float_as_int(v), 0x111, 0xF, 0xF, true);
    return __int_as_float(r);
}
__device__ __forceinline__ float dpp_from_right(float v) {
    // lane i gets lane i+1's v; qx==15 -> 0.
    int r = __builtin_amdgcn_update_dpp(0, __float_as_int(v), 0x101, 0xF, 0xF, true);
    return __int_as_float(r);
}

// ---------------------------------------------------------------------------
// Kernel 1: normalize guidance -> fp16 weights (AoS), fp16 bias, fp16 state.
// ---------------------------------------------------------------------------
__global__ __launch_bounds__(256) void precompute_kernel(
    const float* __restrict__ guidance, const float* __restrict__ raw,
    half8* __restrict__ wgt, _Float16* __restrict__ bias,
    _Float16* __restrict__ state, int B, int H, int W)
{
    int idx = blockIdx.x * blockDim.x + threadIdx.x;
    int total = B * H * W;
    if (idx >= total) return;
    int x = idx % W;
    int y = (idx / W) % H;
    int b = idx / (W * H);

    const int dy[8] = {-1,-1,-1, 0, 0, 1, 1, 1};
    const int dx[8] = {-1, 0, 1,-1, 1,-1, 0, 1};

    float g[8];
    float s = 0.f;
#pragma unroll
    for (int c = 0; c < 8; ++c) {
        int yy = y + dy[c], xx = x + dx[c];
        float v = 0.f;
        if (yy >= 0 && yy < H && xx >= 0 && xx < W)
            v = guidance[(((size_t)b * 8 + c) * H + yy) * W + xx];
        g[c] = v;
        s += fabsf(v);
    }
    float inv = 1.f / fmaxf(s, EPSV);
    float wsum = 0.f;
#pragma unroll
    for (int c = 0; c < 8; ++c) { g[c] *= inv; wsum += g[c]; }

    half8 hw;
#pragma unroll
    for (int c = 0; c < 8; ++c) hw[c] = (_Float16)g[c];
    wgt[idx] = hw;

    float r = raw[idx];
    bias[idx]  = (_Float16)((1.f - wsum) * r);
    state[idx] = (_Float16)r;
}

// ---------------------------------------------------------------------------
// Kernel 2: FUSE Jacobi iterations with state in registers.
// Tile = 64x64 owned px; outside-tile treated as 0 each iteration (recompute
// ring): after k iters px at distance >= k from tile edge are exact, so the
// 48x48 core (distance 8) is exact at k=FUSE=8. Out-of-image px have
// w=0,b=0,s=0 -> stay 0, matching zero-pad semantics. Cores tile the image
// disjointly, so the last launch writes every output px exactly once.
// ---------------------------------------------------------------------------
template<bool LAST>
__global__ __launch_bounds__(256) void prop_fused_kernel(
    const _Float16* __restrict__ src, const half8* __restrict__ wgt,
    const _Float16* __restrict__ bias, _Float16* __restrict__ dst,
    float* __restrict__ dst32)
{
    const int H = 480, W = 640;
    // bufTop[p][s][x]: strip s's row0 (read as "below-row" by strip s-1 at
    // index s; slot 16 stays 0). bufBot[p][s+1][x]: strip s's row3 (read as
    // "above-row" by strip s+1 at index s+1; slot 0 stays 0).
    __shared__ __align__(16) float bufTop[2][17][64];
    __shared__ __align__(16) float bufBot[2][17][64];

    int tid = threadIdx.x;
    int qx = tid & 15;          // x-quad within tile (DPP row position)
    int sy = tid >> 4;          // 4-row strip within tile

    int t = blockIdx.x;
    int tx = t % TXN;
    int tmp = t / TXN;
    int ty = tmp % TYN;
    int b  = tmp / TYN;
    int x0 = tx * CORE - FUSE;
    int y0 = ty * CORE - FUSE;
    size_t plane = (size_t)b * H * W;

    int gx0 = x0 + qx * 4;                       // quad is fully in or out
    bool xok = (gx0 >= 0) & (gx0 + 3 < W);
    int gyb = y0 + sy * 4;

    if (tid < 64) {
        bufBot[0][0][tid]  = 0.f; bufBot[1][0][tid]  = 0.f;
        bufTop[0][16][tid] = 0.f; bufTop[1][16][tid] = 0.f;
    }

    // Per-px weights (half8 = 4 VGPR), bias f32, state f32 — all static-indexed.
    half8 pw[4][4];
    float pb[4][4];
    float s[4][4];
#pragma unroll
    for (int r = 0; r < 4; ++r) {
        int gy = gyb + r;
        bool ok = xok && gy >= 0 && gy < H;
        if (ok) {
            size_t gb = plane + (size_t)gy * W + gx0;
            const half8* wp = wgt + gb;
            pw[r][0] = wp[0]; pw[r][1] = wp[1]; pw[r][2] = wp[2]; pw[r][3] = wp[3];
            half4 bq = *(const half4*)(bias + gb);
            half4 sq = *(const half4*)(src + gb);
#pragma unroll
            for (int c = 0; c < 4; ++c) {
                pb[r][c] = (float)bq[c];
                s[r][c]  = (float)sq[c];
            }
        } else {
            half8 hz;
#pragma unroll
            for (int c = 0; c < 8; ++c) hz[c] = (_Float16)0.f;
#pragma unroll
            for (int c = 0; c < 4; ++c) {
                pw[r][c] = hz; pb[r][c] = 0.f; s[r][c] = 0.f;
            }
        }
    }

#pragma unroll 2
    for (int it = 0; it < FUSE; ++it) {
        const int p = it & 1;
        // Exchange strip-boundary rows (old values).
        *(float4*)&bufTop[p][sy][qx * 4]     = make_float4(s[0][0], s[0][1], s[0][2], s[0][3]);
        *(float4*)&bufBot[p][sy + 1][qx * 4] = make_float4(s[3][0], s[3][1], s[3][2], s[3][3]);
        __syncthreads();
        float4 Av = *(const float4*)&bufBot[p][sy][qx * 4];      // row above strip
        float4 Bv = *(const float4*)&bufTop[p][sy + 1][qx * 4];  // row below strip

        // Rolling in-place update (wave-uniform, so DPP of carry regs is safe).
        float u0 = Av.x, u1 = Av.y, u2 = Av.z, u3 = Av.w;
        float ul = dpp_from_left(u3);
        float ur = dpp_from_right(u0);
        float cl = dpp_from_left(s[0][3]);
        float cr = dpp_from_right(s[0][0]);
#pragma unroll
        for (int r = 0; r < 4; ++r) {
            float D0, D1, D2, D3;
            if (r < 3) { D0 = s[r+1][0]; D1 = s[r+1][1]; D2 = s[r+1][2]; D3 = s[r+1][3]; }
            else       { D0 = Bv.x;      D1 = Bv.y;      D2 = Bv.z;      D3 = Bv.w; }
            float dl = dpp_from_left(D3);
            float dr = dpp_from_right(D0);
            float C0 = s[r][0], C1 = s[r][1], C2 = s[r][2], C3 = s[r][3];
            half8 w0 = pw[r][0], w1 = pw[r][1], w2 = pw[r][2], w3 = pw[r][3];
            float n0 = pb[r][0]
                + (float)w0[0] * ul + (float)w0[1] * u0 + (float)w0[2] * u1
                + (float)w0[3] * cl + (float)w0[4] * C1
                + (float)w0[5] * dl + (float)w0[6] * D0 + (float)w0[7] * D1;
            float n1 = pb[r][1]
                + (float)w1[0] * u0 + (float)w1[1] * u1 + (float)w1[2] * u2
                + (float)w1[3] * C0 + (float)w1[4] * C2
                + (float)w1[5] * D0 + (float)w1[6] * D1 + (float)w1[7] * D2;
            float n2 = pb[r][2]
                + (float)w2[0] * u1 + (float)w2[1] * u2 + (float)w2[2] * u3
                + (float)w2[3] * C1 + (float)w2[4] * C3
                + (float)w2[5] * D1 + (float)w2[6] * D2 + (float)w2[7] * D3;
            float n3 = pb[r][3]
                + (float)w3[0] * u2 + (float)w3[1] * u3 + (float)w3[2] * ur
                + (float)w3[3] * C2 + (float)w3[4] * cr
                + (float)w3[5] * D2 + (float)w3[6] * D3 + (float)w3[7] * dr;
            u0 = C0; u1 = C1; u2 = C2; u3 = C3; ul = cl; ur = cr;
            cl = dl; cr = dr;
            s[r][0] = n0; s[r][1] = n1; s[r][2] = n2; s[r][3] = n3;
        }
    }

    // Store the 48x48 core (strips/quads 2..13 inclusive).
    bool core = (qx >= 2) & (qx < 14) & (sy >= 2) & (sy < 14);
    if (core && xok) {
#pragma unroll
        for (int r = 0; r < 4; ++r) {
            int gy = gyb + r;                       // in [0,480) by construction
            size_t gb = plane + (size_t)gy * W + gx0;
            if (LAST) {
                *(float4*)(dst32 + gb) = make_float4(s[r][0], s[r][1], s[r][2], s[r][3]);
            } else {
                half4 hv;
                hv[0] = (_Float16)s[r][0]; hv[1] = (_Float16)s[r][1];
                hv[2] = (_Float16)s[r][2]; hv[3] = (_Float16)s[r][3];
                *(half4*)(dst + gb) = hv;
            }
        }
    }
}

// ---------------------------------------------------------------------------
extern "C" void kernel_launch(void* const* d_in, const int* in_sizes, int n_in,
                              void* d_out, int out_size, void* d_ws, size_t ws_size,
                              hipStream_t stream) {
    const float* guidance = (const float*)d_in[0];
    const float* raw      = (const float*)d_in[1];
    float* out = (float*)d_out;

    const int B = 8, H = 480, W = 640;
    const size_t npix = (size_t)B * H * W;

    // Workspace: wgt half8 (npix*16B) | bias fp16 | p0 fp16 | p1 fp16
    half8*    wgt  = (half8*)d_ws;
    _Float16* bias = (_Float16*)((char*)d_ws + npix * sizeof(half8));
    _Float16* p0   = bias + npix;
    _Float16* p1   = p0 + npix;

    {
        int blocks = (int)((npix + 255) / 256);
        precompute_kernel<<<blocks, 256, 0, stream>>>(guidance, raw, wgt, bias,
                                                      p0, B, H, W);
    }

    // 3 launches x FUSE=8 = 24 iterations. p0 -> p1 -> p0 -> out(f32).
    prop_fused_kernel<false><<<NBLK, 256, 0, stream>>>(p0, wgt, bias, p1, nullptr);
    prop_fused_kernel<false><<<NBLK, 256, 0, stream>>>(p1, wgt, bias, p0, nullptr);
    prop_fused_kernel<true ><<<NBLK, 256, 0, stream>>>(p0, wgt, bias, nullptr, out);
}